// Round 2
// baseline (123.790 us; speedup 1.0000x reference)
//
#include <hip/hip_runtime.h>
#include <stdint.h>

#define BATCH 2048
#define INF 1024
#define OUTF 1024
#define GRID_G 8
#define KTOT 9216   // INF + INF*GRID_G

#define BM 128
#define BN 128
#define BK 32
#define SK 8
#define KC (KTOT / SK)   // 1152
#define MT (BATCH / BM)  // 16
#define NT (OUTF / BN)   // 8

typedef __attribute__((ext_vector_type(8))) short short8_t;
typedef __attribute__((ext_vector_type(4))) float f32x4_t;
typedef __attribute__((ext_vector_type(8))) unsigned short u16x8_t;

__device__ __forceinline__ unsigned short f2bf(float f) {
  unsigned int u = __float_as_uint(f);
  u += 0x7FFFu + ((u >> 16) & 1u);
  return (unsigned short)(u >> 16);
}

__device__ __forceinline__ void async16(void* lds, const void* g) {
  __builtin_amdgcn_global_load_lds(
      (const __attribute__((address_space(1))) void*)g,
      (__attribute__((address_space(3))) void*)lds, 16, 0, 0);
}

// Build W_cat[o][k]: k<1024 -> bf16(base_weight[o][k]); else bf16(coeff[o][k-1024])
// (spline_coeff (O,I,G) row-major == [o][8i+g] already)
__global__ __launch_bounds__(256) void build_w_kernel(
    const float* __restrict__ bw, const float* __restrict__ coeff,
    unsigned short* __restrict__ wc) {
  int id = blockIdx.x * 256 + threadIdx.x;  // one thread per 8 elements
  int row = id / (KTOT / 8);
  int k8 = id - row * (KTOT / 8);
  int k = k8 * 8;
  const float* src = (k < INF) ? (bw + (size_t)row * INF + k)
                               : (coeff + (size_t)row * (INF * GRID_G) + (k - INF));
  const float4* s4 = (const float4*)src;
  float4 a = s4[0], b = s4[1];
  u16x8_t v;
  v[0] = f2bf(a.x); v[1] = f2bf(a.y); v[2] = f2bf(a.z); v[3] = f2bf(a.w);
  v[4] = f2bf(b.x); v[5] = f2bf(b.y); v[6] = f2bf(b.z); v[7] = f2bf(b.w);
  *(u16x8_t*)(wc + (size_t)id * 8) = v;
}

// Build A_cat[b][k]: k<1024 -> bf16(x[b][k]); spline block: one-hot(idx)*bf16(0.1*w)
__global__ __launch_bounds__(256) void build_a_kernel(
    const float* __restrict__ x, const float* __restrict__ grid,
    unsigned short* __restrict__ ac) {
  __shared__ float sg[GRID_G + 1];
  if (threadIdx.x <= GRID_G) sg[threadIdx.x] = grid[threadIdx.x];
  __syncthreads();
  int id = blockIdx.x * 256 + threadIdx.x;  // one per (b,i)
  int b = id >> 10;
  int i = id & 1023;
  float xv = x[id];
  ac[(size_t)b * KTOT + i] = f2bf(xv);
  float xc = fminf(fmaxf(xv, -1.0f), 1.0f);
  int cnt = 0;
#pragma unroll
  for (int j = 0; j <= GRID_G; ++j) cnt += (xc >= sg[j]) ? 1 : 0;
  int idx = cnt - 1;
  idx = idx < 0 ? 0 : (idx > GRID_G - 1 ? GRID_G - 1 : idx);
  float left = sg[idx], right = sg[idx + 1];
  float denom = right - left;
  denom = (denom == 0.0f) ? 1.0f : denom;
  float w = (xc - left) / denom;
  unsigned short val = f2bf(0.1f * w);
  u16x8_t v;
#pragma unroll
  for (int g = 0; g < GRID_G; ++g) v[g] = (g == idx) ? val : (unsigned short)0;
  *(u16x8_t*)(ac + (size_t)b * KTOT + INF + (size_t)i * 8) = v;
}

// Split-K bf16 GEMM, m97-style structure + read-side XOR swizzle + XCD swizzle.
// LDS tile layout: linear row-major [128][32] per matrix, written by
// global_load_lds (wave-uniform base + lane*16B). Logical element (r, chunk k)
// [chunk = 16B = 8 bf16] is stored at chunk (k ^ (r&3)): we pre-swizzle the
// GLOBAL source column per lane (rule: linear dest + inv-swz source + swz read).
// Reads then use chunk lk^(lr&3) -> lane-constant, 8-way -> 4-way conflict.
__global__ __launch_bounds__(256) void gemm_kernel(
    const unsigned short* __restrict__ A, const unsigned short* __restrict__ W,
    float* __restrict__ out) {
  __shared__ unsigned short As[BM * BK];  // 8 KB
  __shared__ unsigned short Bs[BN * BK];  // 8 KB

  // XCD-aware bijective swizzle: 1024 blocks, 8 XCDs -> XCD x owns sk-slab x.
  int bid = blockIdx.x;
  int wgid = (bid & 7) * (SK * MT * NT / 8) + (bid >> 3);
  int sk = wgid >> 7;          // /128
  int t = wgid & 127;
  int mt = t >> 3;             // /NT
  int nt = t & 7;

  int tid = threadIdx.x;
  int wave = tid >> 6;
  int lane = tid & 63;
  int wm = wave >> 1, wn = wave & 1;  // 2x2 wave grid, 64x64 per wave
  int lr = lane & 15, lk = lane >> 4;

  // staging: chunk = 16 rows x 32 cols (1KB); lane l -> row l>>2, src col-chunk
  // pre-swizzled: (l&3) ^ ((l>>2)&3)
  int srow = lane >> 2;
  int schunk = (lane & 3) ^ (srow & 3);
  int scol = schunk * 8;
  const unsigned short* ga0 = A + (size_t)(mt * BM + wave * 32 + 0 + srow) * KTOT + sk * KC + scol;
  const unsigned short* ga1 = A + (size_t)(mt * BM + wave * 32 + 16 + srow) * KTOT + sk * KC + scol;
  const unsigned short* gb0 = W + (size_t)(nt * BN + wave * 32 + 0 + srow) * KTOT + sk * KC + scol;
  const unsigned short* gb1 = W + (size_t)(nt * BN + wave * 32 + 16 + srow) * KTOT + sk * KC + scol;
  unsigned short* la0 = &As[(wave * 2 + 0) * 512];
  unsigned short* la1 = &As[(wave * 2 + 1) * 512];
  unsigned short* lb0 = &Bs[(wave * 2 + 0) * 512];
  unsigned short* lb1 = &Bs[(wave * 2 + 1) * 512];

  // swizzled read col offset (elements): lane-constant
  int rc = ((lk ^ (lr & 3)) * 8);

  f32x4_t acc[4][4];
#pragma unroll
  for (int i2 = 0; i2 < 4; ++i2)
#pragma unroll
    for (int j2 = 0; j2 < 4; ++j2) acc[i2][j2] = f32x4_t{0.0f, 0.0f, 0.0f, 0.0f};

  for (int kt = 0; kt < KC / BK; ++kt) {
    async16(la0, ga0);
    async16(la1, ga1);
    async16(lb0, gb0);
    async16(lb1, gb1);
    ga0 += BK; ga1 += BK; gb0 += BK; gb1 += BK;
    __syncthreads();  // drains vmcnt -> LDS tiles ready

    short8_t af[4], bf[4];
#pragma unroll
    for (int mi = 0; mi < 4; ++mi)
      af[mi] = *(const short8_t*)&As[(wm * 64 + mi * 16 + lr) * BK + rc];
#pragma unroll
    for (int ni = 0; ni < 4; ++ni)
      bf[ni] = *(const short8_t*)&Bs[(wn * 64 + ni * 16 + lr) * BK + rc];
#pragma unroll
    for (int mi = 0; mi < 4; ++mi)
#pragma unroll
      for (int ni = 0; ni < 4; ++ni)
        acc[mi][ni] = __builtin_amdgcn_mfma_f32_16x16x32_bf16(af[mi], bf[ni], acc[mi][ni], 0, 0, 0);
    __syncthreads();  // before overwriting LDS next iter
  }

  // epilogue: C/D layout col=lane&15 (n), row=(lane>>4)*4+reg (m)
#pragma unroll
  for (int mi = 0; mi < 4; ++mi) {
#pragma unroll
    for (int ni = 0; ni < 4; ++ni) {
      int col = nt * BN + wn * 64 + ni * 16 + lr;
#pragma unroll
      for (int r = 0; r < 4; ++r) {
        int rowm = mt * BM + wm * 64 + mi * 16 + lk * 4 + r;
        atomicAdd(&out[(size_t)rowm * OUTF + col], acc[mi][ni][r]);
      }
    }
  }
}

extern "C" void kernel_launch(void* const* d_in, const int* in_sizes, int n_in,
                              void* d_out, int out_size, void* d_ws, size_t ws_size,
                              hipStream_t stream) {
  const float* x = (const float*)d_in[0];
  const float* bw = (const float*)d_in[1];
  const float* coeff = (const float*)d_in[2];
  const float* grid = (const float*)d_in[3];
  float* out = (float*)d_out;

  unsigned short* Acat = (unsigned short*)d_ws;              // 2048*9216*2 = 37.75 MB
  unsigned short* Wcat = Acat + (size_t)BATCH * KTOT;        // 1024*9216*2 = 18.87 MB

  hipMemsetAsync(d_out, 0, (size_t)out_size * sizeof(float), stream);
  build_w_kernel<<<OUTF * (KTOT / 8) / 256, 256, 0, stream>>>(bw, coeff, Wcat);
  build_a_kernel<<<BATCH * INF / 256, 256, 0, stream>>>(x, grid, Acat);
  gemm_kernel<<<SK * MT * NT, 256, 0, stream>>>(Acat, Wcat, out);
}

// Round 3
// 94.765 us; speedup vs baseline: 1.3063x; 1.3063x over previous
//
#include <hip/hip_runtime.h>
#include <stdint.h>

#define BATCH 2048
#define INF 1024
#define OUTF 1024
#define GRID_G 8
#define KTOT 9216   // INF + INF*GRID_G

#define BM 128
#define BN 128
#define BK 32
#define SK 8
#define KC (KTOT / SK)   // 1152
#define MT (BATCH / BM)  // 16
#define NT (OUTF / BN)   // 8
#define CSLAB ((size_t)BATCH * OUTF)  // 2097152 elements per partial slab

typedef __attribute__((ext_vector_type(8))) short short8_t;
typedef __attribute__((ext_vector_type(4))) float f32x4_t;
typedef __attribute__((ext_vector_type(8))) unsigned short u16x8_t;

__device__ __forceinline__ unsigned short f2bf(float f) {
  unsigned int u = __float_as_uint(f);
  u += 0x7FFFu + ((u >> 16) & 1u);
  return (unsigned short)(u >> 16);
}

__device__ __forceinline__ void async16(void* lds, const void* g) {
  __builtin_amdgcn_global_load_lds(
      (const __attribute__((address_space(1))) void*)g,
      (__attribute__((address_space(3))) void*)lds, 16, 0, 0);
}

// Build W_cat[o][k]: k<1024 -> bf16(base_weight[o][k]); else bf16(coeff[o][k-1024])
// (spline_coeff (O,I,G) row-major == [o][8i+g] already)
__global__ __launch_bounds__(256) void build_w_kernel(
    const float* __restrict__ bw, const float* __restrict__ coeff,
    unsigned short* __restrict__ wc) {
  int id = blockIdx.x * 256 + threadIdx.x;  // one thread per 8 elements
  int row = id / (KTOT / 8);
  int k8 = id - row * (KTOT / 8);
  int k = k8 * 8;
  const float* src = (k < INF) ? (bw + (size_t)row * INF + k)
                               : (coeff + (size_t)row * (INF * GRID_G) + (k - INF));
  const float4* s4 = (const float4*)src;
  float4 a = s4[0], b = s4[1];
  u16x8_t v;
  v[0] = f2bf(a.x); v[1] = f2bf(a.y); v[2] = f2bf(a.z); v[3] = f2bf(a.w);
  v[4] = f2bf(b.x); v[5] = f2bf(b.y); v[6] = f2bf(b.z); v[7] = f2bf(b.w);
  *(u16x8_t*)(wc + (size_t)id * 8) = v;
}

// Build A_cat[b][k]: k<1024 -> bf16(x[b][k]); spline block: one-hot(idx)*bf16(0.1*w)
__global__ __launch_bounds__(256) void build_a_kernel(
    const float* __restrict__ x, const float* __restrict__ grid,
    unsigned short* __restrict__ ac) {
  __shared__ float sg[GRID_G + 1];
  if (threadIdx.x <= GRID_G) sg[threadIdx.x] = grid[threadIdx.x];
  __syncthreads();
  int id = blockIdx.x * 256 + threadIdx.x;  // one per (b,i)
  int b = id >> 10;
  int i = id & 1023;
  float xv = x[id];
  ac[(size_t)b * KTOT + i] = f2bf(xv);
  float xc = fminf(fmaxf(xv, -1.0f), 1.0f);
  int cnt = 0;
#pragma unroll
  for (int j = 0; j <= GRID_G; ++j) cnt += (xc >= sg[j]) ? 1 : 0;
  int idx = cnt - 1;
  idx = idx < 0 ? 0 : (idx > GRID_G - 1 ? GRID_G - 1 : idx);
  float left = sg[idx], right = sg[idx + 1];
  float denom = right - left;
  denom = (denom == 0.0f) ? 1.0f : denom;
  float w = (xc - left) / denom;
  unsigned short val = f2bf(0.1f * w);
  u16x8_t v;
#pragma unroll
  for (int g = 0; g < GRID_G; ++g) v[g] = (g == idx) ? val : (unsigned short)0;
  *(u16x8_t*)(ac + (size_t)b * KTOT + INF + (size_t)i * 8) = v;
}

// Split-K bf16 GEMM, m97 structure. Each block writes a PRIVATE bf16 partial
// slab P[sk] (no atomics, no cross-block interaction). 1024 blocks = 4/CU.
__global__ __launch_bounds__(256) void gemm_kernel(
    const unsigned short* __restrict__ A, const unsigned short* __restrict__ W,
    unsigned short* __restrict__ P) {
  __shared__ unsigned short As[BM * BK];  // 8 KB
  __shared__ unsigned short Bs[BN * BK];  // 8 KB

  int bid = blockIdx.x;        // sk-major: partners for a tile are 128 apart
  int sk = bid >> 7;
  int t = bid & 127;
  int mt = t >> 3;
  int nt = t & 7;

  int tid = threadIdx.x;
  int wave = tid >> 6;
  int lane = tid & 63;
  int wm = wave >> 1, wn = wave & 1;  // 2x2 wave grid, 64x64 per wave
  int lr = lane & 15, lk = lane >> 4;

  // staging: each async16 moves 16 rows x 32 cols (1KB); lane l -> row l>>2,
  // col (l&3)*8 — matches linear LDS dest (base + lane*16B)
  int srow = lane >> 2;
  int scol = (lane & 3) * 8;
  const unsigned short* ga0 = A + (size_t)(mt * BM + wave * 32 + 0 + srow) * KTOT + sk * KC + scol;
  const unsigned short* ga1 = A + (size_t)(mt * BM + wave * 32 + 16 + srow) * KTOT + sk * KC + scol;
  const unsigned short* gb0 = W + (size_t)(nt * BN + wave * 32 + 0 + srow) * KTOT + sk * KC + scol;
  const unsigned short* gb1 = W + (size_t)(nt * BN + wave * 32 + 16 + srow) * KTOT + sk * KC + scol;
  unsigned short* la0 = &As[(wave * 2 + 0) * 512];
  unsigned short* la1 = &As[(wave * 2 + 1) * 512];
  unsigned short* lb0 = &Bs[(wave * 2 + 0) * 512];
  unsigned short* lb1 = &Bs[(wave * 2 + 1) * 512];

  f32x4_t acc[4][4];
#pragma unroll
  for (int i2 = 0; i2 < 4; ++i2)
#pragma unroll
    for (int j2 = 0; j2 < 4; ++j2) acc[i2][j2] = f32x4_t{0.0f, 0.0f, 0.0f, 0.0f};

  for (int kt = 0; kt < KC / BK; ++kt) {
    async16(la0, ga0);
    async16(la1, ga1);
    async16(lb0, gb0);
    async16(lb1, gb1);
    ga0 += BK; ga1 += BK; gb0 += BK; gb1 += BK;
    __syncthreads();  // drains vmcnt -> LDS tiles ready

    short8_t af[4], bf[4];
#pragma unroll
    for (int mi = 0; mi < 4; ++mi)
      af[mi] = *(const short8_t*)&As[(wm * 64 + mi * 16 + lr) * BK + lk * 8];
#pragma unroll
    for (int ni = 0; ni < 4; ++ni)
      bf[ni] = *(const short8_t*)&Bs[(wn * 64 + ni * 16 + lr) * BK + lk * 8];
#pragma unroll
    for (int mi = 0; mi < 4; ++mi)
#pragma unroll
      for (int ni = 0; ni < 4; ++ni)
        acc[mi][ni] = __builtin_amdgcn_mfma_f32_16x16x32_bf16(af[mi], bf[ni], acc[mi][ni], 0, 0, 0);
    __syncthreads();  // before overwriting LDS next iter
  }

  // epilogue: C/D layout col=lane&15 (n), row=(lane>>4)*4+reg (m).
  // Private slab -> plain stores, bf16 partials.
  unsigned short* slab = P + (size_t)sk * CSLAB;
#pragma unroll
  for (int mi = 0; mi < 4; ++mi) {
#pragma unroll
    for (int ni = 0; ni < 4; ++ni) {
      int col = nt * BN + wn * 64 + ni * 16 + lr;
#pragma unroll
      for (int r = 0; r < 4; ++r) {
        int rowm = mt * BM + wm * 64 + mi * 16 + lk * 4 + r;
        slab[(size_t)rowm * OUTF + col] = f2bf(acc[mi][ni][r]);
      }
    }
  }
}

// out[e] = sum_sk P[sk][e]; 8 elements/thread, fully overwrites d_out.
__global__ __launch_bounds__(256) void reduce_kernel(
    const unsigned short* __restrict__ P, float* __restrict__ out) {
  size_t base = ((size_t)blockIdx.x * 256 + threadIdx.x) * 8;
  float s[8];
#pragma unroll
  for (int j = 0; j < 8; ++j) s[j] = 0.0f;
#pragma unroll
  for (int k = 0; k < SK; ++k) {
    u16x8_t v = *(const u16x8_t*)(P + (size_t)k * CSLAB + base);
#pragma unroll
    for (int j = 0; j < 8; ++j)
      s[j] += __uint_as_float((unsigned int)v[j] << 16);
  }
  float4 lo = {s[0], s[1], s[2], s[3]};
  float4 hi = {s[4], s[5], s[6], s[7]};
  *(float4*)(out + base) = lo;
  *(float4*)(out + base + 4) = hi;
}

extern "C" void kernel_launch(void* const* d_in, const int* in_sizes, int n_in,
                              void* d_out, int out_size, void* d_ws, size_t ws_size,
                              hipStream_t stream) {
  const float* x = (const float*)d_in[0];
  const float* bw = (const float*)d_in[1];
  const float* coeff = (const float*)d_in[2];
  const float* grid = (const float*)d_in[3];
  float* out = (float*)d_out;

  unsigned short* Acat = (unsigned short*)d_ws;              // 2048*9216*2 = 37.75 MB
  unsigned short* Wcat = Acat + (size_t)BATCH * KTOT;        // 1024*9216*2 = 18.87 MB
  unsigned short* Part = Wcat + (size_t)OUTF * KTOT;         // 8 * 4 MB   = 33.55 MB

  build_w_kernel<<<OUTF * (KTOT / 8) / 256, 256, 0, stream>>>(bw, coeff, Wcat);
  build_a_kernel<<<BATCH * INF / 256, 256, 0, stream>>>(x, grid, Acat);
  gemm_kernel<<<SK * MT * NT, 256, 0, stream>>>(Acat, Wcat, Part);
  reduce_kernel<<<(int)(CSLAB / 8 / 256), 256, 0, stream>>>(Part, out);
}

// Round 4
// 84.278 us; speedup vs baseline: 1.4688x; 1.1244x over previous
//
#include <hip/hip_runtime.h>
#include <stdint.h>

#define BATCH 2048
#define INF 1024
#define OUTF 1024
#define GRID_G 8
#define KTOT 9216   // INF + INF*GRID_G

#define BM 128
#define BN 128
#define BK 32
#define SK 8
#define KC (KTOT / SK)   // 1152
#define NKT (KC / BK)    // 36
#define MT (BATCH / BM)  // 16
#define NT (OUTF / BN)   // 8
#define CSLAB ((size_t)BATCH * OUTF)  // elements per partial slab

typedef __attribute__((ext_vector_type(8))) short short8_t;
typedef __attribute__((ext_vector_type(4))) float f32x4_t;
typedef __attribute__((ext_vector_type(8))) unsigned short u16x8_t;

__device__ __forceinline__ unsigned short f2bf(float f) {
  unsigned int u = __float_as_uint(f);
  u += 0x7FFFu + ((u >> 16) & 1u);
  return (unsigned short)(u >> 16);
}

__device__ __forceinline__ void async16(void* lds, const void* g) {
  __builtin_amdgcn_global_load_lds(
      (const __attribute__((address_space(1))) void*)g,
      (__attribute__((address_space(3))) void*)lds, 16, 0, 0);
}

// Build W_cat[o][k]: k<1024 -> bf16(base_weight[o][k]); else bf16(coeff[o][k-1024])
__global__ __launch_bounds__(256) void build_w_kernel(
    const float* __restrict__ bw, const float* __restrict__ coeff,
    unsigned short* __restrict__ wc) {
  int id = blockIdx.x * 256 + threadIdx.x;  // one thread per 8 elements
  int row = id / (KTOT / 8);
  int k8 = id - row * (KTOT / 8);
  int k = k8 * 8;
  const float* src = (k < INF) ? (bw + (size_t)row * INF + k)
                               : (coeff + (size_t)row * (INF * GRID_G) + (k - INF));
  const float4* s4 = (const float4*)src;
  float4 a = s4[0], b = s4[1];
  u16x8_t v;
  v[0] = f2bf(a.x); v[1] = f2bf(a.y); v[2] = f2bf(a.z); v[3] = f2bf(a.w);
  v[4] = f2bf(b.x); v[5] = f2bf(b.y); v[6] = f2bf(b.z); v[7] = f2bf(b.w);
  *(u16x8_t*)(wc + (size_t)id * 8) = v;
}

// Build A_cat[b][k]: k<1024 -> bf16(x[b][k]); spline block: one-hot(idx)*bf16(0.1*w)
__global__ __launch_bounds__(256) void build_a_kernel(
    const float* __restrict__ x, const float* __restrict__ grid,
    unsigned short* __restrict__ ac) {
  __shared__ float sg[GRID_G + 1];
  if (threadIdx.x <= GRID_G) sg[threadIdx.x] = grid[threadIdx.x];
  __syncthreads();
  int id = blockIdx.x * 256 + threadIdx.x;  // one per (b,i)
  int b = id >> 10;
  int i = id & 1023;
  float xv = x[id];
  ac[(size_t)b * KTOT + i] = f2bf(xv);
  float xc = fminf(fmaxf(xv, -1.0f), 1.0f);
  int cnt = 0;
#pragma unroll
  for (int j = 0; j <= GRID_G; ++j) cnt += (xc >= sg[j]) ? 1 : 0;
  int idx = cnt - 1;
  idx = idx < 0 ? 0 : (idx > GRID_G - 1 ? GRID_G - 1 : idx);
  float left = sg[idx], right = sg[idx + 1];
  float denom = right - left;
  denom = (denom == 0.0f) ? 1.0f : denom;
  float w = (xc - left) / denom;
  unsigned short val = f2bf(0.1f * w);
  u16x8_t v;
#pragma unroll
  for (int g = 0; g < GRID_G; ++g) v[g] = (g == idx) ? val : (unsigned short)0;
  *(u16x8_t*)(ac + (size_t)b * KTOT + INF + (size_t)i * 8) = v;
}

// Split-K bf16 GEMM, 2-phase double-buffered pipeline + XCD<->sk affinity.
// Per iteration: barrier (drains prev stage, had a full compute phase to
// complete) -> issue next-tile global_load_lds into buf^1 -> ds_read+MFMA buf.
__global__ __launch_bounds__(256) void gemm_kernel(
    const unsigned short* __restrict__ A, const unsigned short* __restrict__ W,
    unsigned short* __restrict__ P) {
  __shared__ unsigned short As[2][BM * BK];  // 2 x 8 KB
  __shared__ unsigned short Bs[2][BN * BK];  // 2 x 8 KB

  int bid = blockIdx.x;
  // round-robin dispatch: bid%8 -> XCD; give each XCD one sk-slab (7 MB -> L2)
  int sk = bid & 7;
  int t = bid >> 3;            // [0,128)
  int mt = t >> 3;
  int nt = t & 7;

  int tid = threadIdx.x;
  int wave = tid >> 6;
  int lane = tid & 63;
  int wm = wave >> 1, wn = wave & 1;  // 2x2 wave grid, 64x64 per wave
  int lr = lane & 15, lk = lane >> 4;

  // staging: each async16 moves one 16-row x 32-col chunk (1KB/wave-instr);
  // lane l -> row l>>2, col (l&3)*8 ; matches linear LDS dest (base+lane*16B)
  int srow = lane >> 2;
  int scol = (lane & 3) * 8;
  const unsigned short* ga0 = A + (size_t)(mt * BM + wave * 32 + 0 + srow) * KTOT + sk * KC + scol;
  const unsigned short* ga1 = A + (size_t)(mt * BM + wave * 32 + 16 + srow) * KTOT + sk * KC + scol;
  const unsigned short* gb0 = W + (size_t)(nt * BN + wave * 32 + 0 + srow) * KTOT + sk * KC + scol;
  const unsigned short* gb1 = W + (size_t)(nt * BN + wave * 32 + 16 + srow) * KTOT + sk * KC + scol;
  int lofs0 = (wave * 2 + 0) * 512;
  int lofs1 = (wave * 2 + 1) * 512;

  f32x4_t acc[4][4];
#pragma unroll
  for (int i2 = 0; i2 < 4; ++i2)
#pragma unroll
    for (int j2 = 0; j2 < 4; ++j2) acc[i2][j2] = f32x4_t{0.0f, 0.0f, 0.0f, 0.0f};

  // prologue: stage tile 0 into buf 0
  async16(&As[0][lofs0], ga0);
  async16(&As[0][lofs1], ga1);
  async16(&Bs[0][lofs0], gb0);
  async16(&Bs[0][lofs1], gb1);

  for (int kt = 0; kt < NKT; ++kt) {
    int cur = kt & 1;
    __syncthreads();  // drains stage(kt) [auto vmcnt(0)]; also protects buf reuse
    if (kt + 1 < NKT) {
      int nxt = cur ^ 1;
      const unsigned short* pa0 = ga0 + (kt + 1) * BK;
      const unsigned short* pa1 = ga1 + (kt + 1) * BK;
      const unsigned short* pb0 = gb0 + (kt + 1) * BK;
      const unsigned short* pb1 = gb1 + (kt + 1) * BK;
      async16(&As[nxt][lofs0], pa0);
      async16(&As[nxt][lofs1], pa1);
      async16(&Bs[nxt][lofs0], pb0);
      async16(&Bs[nxt][lofs1], pb1);
    }
    short8_t af[4], bf[4];
#pragma unroll
    for (int mi = 0; mi < 4; ++mi)
      af[mi] = *(const short8_t*)&As[cur][(wm * 64 + mi * 16 + lr) * BK + lk * 8];
#pragma unroll
    for (int ni = 0; ni < 4; ++ni)
      bf[ni] = *(const short8_t*)&Bs[cur][(wn * 64 + ni * 16 + lr) * BK + lk * 8];
#pragma unroll
    for (int mi = 0; mi < 4; ++mi)
#pragma unroll
      for (int ni = 0; ni < 4; ++ni)
        acc[mi][ni] = __builtin_amdgcn_mfma_f32_16x16x32_bf16(af[mi], bf[ni], acc[mi][ni], 0, 0, 0);
  }

  // epilogue: C/D layout col=lane&15 (n), row=(lane>>4)*4+reg (m); private slab
  unsigned short* slab = P + (size_t)sk * CSLAB;
#pragma unroll
  for (int mi = 0; mi < 4; ++mi) {
#pragma unroll
    for (int ni = 0; ni < 4; ++ni) {
      int col = nt * BN + wn * 64 + ni * 16 + lr;
#pragma unroll
      for (int r = 0; r < 4; ++r) {
        int rowm = mt * BM + wm * 64 + mi * 16 + lk * 4 + r;
        slab[(size_t)rowm * OUTF + col] = f2bf(acc[mi][ni][r]);
      }
    }
  }
}

// out[e] = sum_sk P[sk][e]; 8 elements/thread, fully overwrites d_out.
__global__ __launch_bounds__(256) void reduce_kernel(
    const unsigned short* __restrict__ P, float* __restrict__ out) {
  size_t base = ((size_t)blockIdx.x * 256 + threadIdx.x) * 8;
  float s[8];
#pragma unroll
  for (int j = 0; j < 8; ++j) s[j] = 0.0f;
#pragma unroll
  for (int k = 0; k < SK; ++k) {
    u16x8_t v = *(const u16x8_t*)(P + (size_t)k * CSLAB + base);
#pragma unroll
    for (int j = 0; j < 8; ++j)
      s[j] += __uint_as_float((unsigned int)v[j] << 16);
  }
  float4 lo = {s[0], s[1], s[2], s[3]};
  float4 hi = {s[4], s[5], s[6], s[7]};
  *(float4*)(out + base) = lo;
  *(float4*)(out + base + 4) = hi;
}

extern "C" void kernel_launch(void* const* d_in, const int* in_sizes, int n_in,
                              void* d_out, int out_size, void* d_ws, size_t ws_size,
                              hipStream_t stream) {
  const float* x = (const float*)d_in[0];
  const float* bw = (const float*)d_in[1];
  const float* coeff = (const float*)d_in[2];
  const float* grid = (const float*)d_in[3];
  float* out = (float*)d_out;

  unsigned short* Acat = (unsigned short*)d_ws;              // 37.75 MB
  unsigned short* Wcat = Acat + (size_t)BATCH * KTOT;        // 18.87 MB
  unsigned short* Part = Wcat + (size_t)OUTF * KTOT;         // 33.55 MB

  build_w_kernel<<<OUTF * (KTOT / 8) / 256, 256, 0, stream>>>(bw, coeff, Wcat);
  build_a_kernel<<<BATCH * INF / 256, 256, 0, stream>>>(x, grid, Acat);
  gemm_kernel<<<SK * MT * NT, 256, 0, stream>>>(Acat, Wcat, Part);
  reduce_kernel<<<(int)(CSLAB / 8 / 256), 256, 0, stream>>>(Part, out);
}

// Round 5
// 71.734 us; speedup vs baseline: 1.7257x; 1.1749x over previous
//
#include <hip/hip_runtime.h>
#include <stdint.h>

#define BATCH 2048
#define INF 1024
#define OUTF 1024
#define GRID_G 8
#define KTOT 9216   // INF + INF*GRID_G

#define BM 256
#define BN 256
#define BK 64
#define SK 8
#define KC (KTOT / SK)   // 1152
#define NKT (KC / BK)    // 18
#define MTT (BATCH / BM) // 8
#define NTT (OUTF / BN)  // 4
#define CSLAB ((size_t)BATCH * OUTF)

typedef __attribute__((ext_vector_type(8))) short short8_t;
typedef __attribute__((ext_vector_type(4))) float f32x4_t;
typedef __attribute__((ext_vector_type(8))) unsigned short u16x8_t;

__device__ __forceinline__ unsigned short f2bf(float f) {
  unsigned int u = __float_as_uint(f);
  u += 0x7FFFu + ((u >> 16) & 1u);
  return (unsigned short)(u >> 16);
}

__device__ __forceinline__ void async16(void* lds, const void* g) {
  __builtin_amdgcn_global_load_lds(
      (const __attribute__((address_space(1))) void*)g,
      (__attribute__((address_space(3))) void*)lds, 16, 0, 0);
}

// Build W_cat[o][k]: k<1024 -> bf16(base_weight[o][k]); else bf16(coeff[o][k-1024])
__global__ __launch_bounds__(256) void build_w_kernel(
    const float* __restrict__ bw, const float* __restrict__ coeff,
    unsigned short* __restrict__ wc) {
  int id = blockIdx.x * 256 + threadIdx.x;  // one thread per 8 elements
  int row = id / (KTOT / 8);
  int k8 = id - row * (KTOT / 8);
  int k = k8 * 8;
  const float* src = (k < INF) ? (bw + (size_t)row * INF + k)
                               : (coeff + (size_t)row * (INF * GRID_G) + (k - INF));
  const float4* s4 = (const float4*)src;
  float4 a = s4[0], b = s4[1];
  u16x8_t v;
  v[0] = f2bf(a.x); v[1] = f2bf(a.y); v[2] = f2bf(a.z); v[3] = f2bf(a.w);
  v[4] = f2bf(b.x); v[5] = f2bf(b.y); v[6] = f2bf(b.z); v[7] = f2bf(b.w);
  *(u16x8_t*)(wc + (size_t)id * 8) = v;
}

// Build A_cat[b][k]: k<1024 -> bf16(x[b][k]); spline block: one-hot(idx)*bf16(0.1*w)
__global__ __launch_bounds__(256) void build_a_kernel(
    const float* __restrict__ x, const float* __restrict__ grid,
    unsigned short* __restrict__ ac) {
  __shared__ float sg[GRID_G + 1];
  if (threadIdx.x <= GRID_G) sg[threadIdx.x] = grid[threadIdx.x];
  __syncthreads();
  int id = blockIdx.x * 256 + threadIdx.x;  // one per (b,i)
  int b = id >> 10;
  int i = id & 1023;
  float xv = x[id];
  ac[(size_t)b * KTOT + i] = f2bf(xv);
  float xc = fminf(fmaxf(xv, -1.0f), 1.0f);
  int cnt = 0;
#pragma unroll
  for (int j = 0; j <= GRID_G; ++j) cnt += (xc >= sg[j]) ? 1 : 0;
  int idx = cnt - 1;
  idx = idx < 0 ? 0 : (idx > GRID_G - 1 ? GRID_G - 1 : idx);
  float left = sg[idx], right = sg[idx + 1];
  float denom = right - left;
  denom = (denom == 0.0f) ? 1.0f : denom;
  float w = (xc - left) / denom;
  unsigned short val = f2bf(0.1f * w);
  u16x8_t v;
#pragma unroll
  for (int g = 0; g < GRID_G; ++g) v[g] = (g == idx) ? val : (unsigned short)0;
  *(u16x8_t*)(ac + (size_t)b * KTOT + INF + (size_t)i * 8) = v;
}

// 256x256x(BK=64) split-K GEMM, 4-phase counted-vmcnt pipeline (8-phase-class
// schedule per 2 K-tiles), XOR-swizzled LDS, raw barriers, setprio.
//
// LDS: LA/LB[buf][ks] regions of 256 rows x 32 cols bf16 (16KB, 64B rows).
// Semantic byte p lives at physical p ^ ((row(p)&3)<<4) (involution within
// a 64B row). Staged by global_load_lds with LINEAR dest (wave base+lane*16)
// and the inverse swizzle applied to each lane's GLOBAL source column.
//
// Per iteration t (tile t in buf c=t&1), phases (ks,ch):
//   gate[vmcnt(4); s_barrier]  -> (0,0): read af(ch0)+bf(k0); stage A(k0,t+1)
//                                 (0,1): read af(ch1);        stage B(k0,t+1)
//   gate[vmcnt(4); s_barrier]  -> (1,0): read af(ch0)+bf(k1); stage A(k1,t+1)
//                                 (1,1): read af(ch1);        stage B(k1,t+1)
// Gate math (steady state): at each gate exactly the 2 half-tiles needed next
// are the oldest 4 outstanding loads -> vmcnt(4) waits precisely for them,
// issued 4 phases earlier. Last iteration uses vmcnt(0) (no prefetch cover).
__global__ __launch_bounds__(512, 2) void gemm_kernel(
    const unsigned short* __restrict__ A, const unsigned short* __restrict__ W,
    unsigned short* __restrict__ P) {
  __shared__ unsigned short LA[2][2][256 * 32];  // 64 KB
  __shared__ unsigned short LB[2][2][256 * 32];  // 64 KB

  int bid = blockIdx.x;
  int sk = bid & 7;          // XCD affinity: one sk-slab per XCD
  int t0 = bid >> 3;         // 0..31
  int mt = t0 >> 2;          // 0..7
  int nt = t0 & 3;           // 0..3

  int tid = threadIdx.x;
  int wave = tid >> 6;
  int lane = tid & 63;
  int wr = wave >> 2, wc = wave & 3;   // 2x4 wave grid; per-wave C = 128x64
  int lr = lane & 15, lk = lane >> 4;
  // swizzled per-lane read offset (elements) within a region, for frag row lr
  int alane = lr * 32 + ((lk * 8) ^ ((lr & 3) << 3));

  // staging source: thread tid covers region rows tid>>2 (load1) and +128
  // (load2); source col pre-swizzled so linear dest == swizzled layout
  int srow = tid >> 2;
  int scol = (((tid & 3) ^ (srow & 3)) << 3);
  const unsigned short* gA  = A + (size_t)(mt * BM + srow) * KTOT + sk * KC + scol;
  const unsigned short* gA2 = gA + (size_t)128 * KTOT;
  const unsigned short* gB  = W + (size_t)(nt * BN + srow) * KTOT + sk * KC + scol;
  const unsigned short* gB2 = gB + (size_t)128 * KTOT;

  f32x4_t acc[2][4][4];
#pragma unroll
  for (int ch = 0; ch < 2; ++ch)
#pragma unroll
    for (int mf = 0; mf < 4; ++mf)
#pragma unroll
      for (int nf = 0; nf < 4; ++nf) acc[ch][mf][nf] = f32x4_t{0.f, 0.f, 0.f, 0.f};

#define STAGE_A(nb, ks_, tt) { \
    unsigned short* d_ = &LA[nb][ks_][wave * 512]; \
    async16(d_, gA + (tt) * BK + (ks_) * 32); \
    async16(d_ + 4096, gA2 + (tt) * BK + (ks_) * 32); }
#define STAGE_B(nb, ks_, tt) { \
    unsigned short* d_ = &LB[nb][ks_][wave * 512]; \
    async16(d_, gB + (tt) * BK + (ks_) * 32); \
    async16(d_ + 4096, gB2 + (tt) * BK + (ks_) * 32); }
#define LOAD_BF(ks_) { _Pragma("unroll") for (int nf = 0; nf < 4; ++nf) \
    bfr[nf] = *(const short8_t*)&LB[c][ks_][(wc * 64 + nf * 16) * 32 + alane]; }
#define LOAD_AF(ks_, ch_) { _Pragma("unroll") for (int mf = 0; mf < 4; ++mf) \
    afr[mf] = *(const short8_t*)&LA[c][ks_][(wr * 128 + (ch_) * 64 + mf * 16) * 32 + alane]; }
#define DO_MFMA(ch_) { __builtin_amdgcn_s_setprio(1); \
    _Pragma("unroll") for (int mf = 0; mf < 4; ++mf) \
    _Pragma("unroll") for (int nf = 0; nf < 4; ++nf) \
      acc[ch_][mf][nf] = __builtin_amdgcn_mfma_f32_16x16x32_bf16( \
          afr[mf], bfr[nf], acc[ch_][mf][nf], 0, 0, 0); \
    __builtin_amdgcn_s_setprio(0); }
#define GATE(pf_) { if (pf_) asm volatile("s_waitcnt vmcnt(4)" ::: "memory"); \
    else asm volatile("s_waitcnt vmcnt(0)" ::: "memory"); \
    __builtin_amdgcn_s_barrier(); \
    asm volatile("" ::: "memory"); }

  // prologue: tile 0 into buf 0, issue order A(k0) B(k0) A(k1) B(k1)
  STAGE_A(0, 0, 0) STAGE_B(0, 0, 0) STAGE_A(0, 1, 0) STAGE_B(0, 1, 0)

  for (int t = 0; t < NKT; ++t) {
    int c = t & 1, nb = c ^ 1;
    int tn = t + 1;
    bool pf = tn < NKT;
    short8_t afr[4], bfr[4];

    GATE(pf)                       // ensures A(k0,t), B(k0,t) landed (all waves)
    LOAD_AF(0, 0) LOAD_BF(0)
    if (pf) STAGE_A(nb, 0, tn)
    DO_MFMA(0)
    LOAD_AF(0, 1)
    if (pf) STAGE_B(nb, 0, tn)
    DO_MFMA(1)

    GATE(pf)                       // ensures A(k1,t), B(k1,t) landed
    LOAD_AF(1, 0) LOAD_BF(1)
    if (pf) STAGE_A(nb, 1, tn)
    DO_MFMA(0)
    LOAD_AF(1, 1)
    if (pf) STAGE_B(nb, 1, tn)
    DO_MFMA(1)
  }

  // epilogue: C/D col=lane&15 (n), row=(lane>>4)*4+reg (m); private bf16 slab
  unsigned short* slab = P + (size_t)sk * CSLAB;
#pragma unroll
  for (int ch = 0; ch < 2; ++ch)
#pragma unroll
    for (int mf = 0; mf < 4; ++mf)
#pragma unroll
      for (int nf = 0; nf < 4; ++nf) {
        int col = nt * BN + wc * 64 + nf * 16 + lr;
        int rowb = mt * BM + wr * 128 + ch * 64 + mf * 16 + lk * 4;
#pragma unroll
        for (int r = 0; r < 4; ++r)
          slab[(size_t)(rowb + r) * OUTF + col] = f2bf(acc[ch][mf][nf][r]);
      }
}

// out[e] = sum_sk P[sk][e]; 8 elements/thread, fully overwrites d_out.
__global__ __launch_bounds__(256) void reduce_kernel(
    const unsigned short* __restrict__ P, float* __restrict__ out) {
  size_t base = ((size_t)blockIdx.x * 256 + threadIdx.x) * 8;
  float s[8];
#pragma unroll
  for (int j = 0; j < 8; ++j) s[j] = 0.0f;
#pragma unroll
  for (int k = 0; k < SK; ++k) {
    u16x8_t v = *(const u16x8_t*)(P + (size_t)k * CSLAB + base);
#pragma unroll
    for (int j = 0; j < 8; ++j)
      s[j] += __uint_as_float((unsigned int)v[j] << 16);
  }
  float4 lo = {s[0], s[1], s[2], s[3]};
  float4 hi = {s[4], s[5], s[6], s[7]};
  *(float4*)(out + base) = lo;
  *(float4*)(out + base + 4) = hi;
}

extern "C" void kernel_launch(void* const* d_in, const int* in_sizes, int n_in,
                              void* d_out, int out_size, void* d_ws, size_t ws_size,
                              hipStream_t stream) {
  const float* x = (const float*)d_in[0];
  const float* bw = (const float*)d_in[1];
  const float* coeff = (const float*)d_in[2];
  const float* grid = (const float*)d_in[3];
  float* out = (float*)d_out;

  unsigned short* Acat = (unsigned short*)d_ws;              // 37.75 MB
  unsigned short* Wcat = Acat + (size_t)BATCH * KTOT;        // 18.87 MB
  unsigned short* Part = Wcat + (size_t)OUTF * KTOT;         // 33.55 MB

  build_w_kernel<<<OUTF * (KTOT / 8) / 256, 256, 0, stream>>>(bw, coeff, Wcat);
  build_a_kernel<<<BATCH * INF / 256, 256, 0, stream>>>(x, grid, Acat);
  gemm_kernel<<<SK * MTT * NTT, 512, 0, stream>>>(Acat, Wcat, Part);
  reduce_kernel<<<(int)(CSLAB / 8 / 256), 256, 0, stream>>>(Part, out);
}